// Round 6
// baseline (373.618 us; speedup 1.0000x reference)
//
#include <hip/hip_runtime.h>

#define B_      8
#define N_      8192
#define M_      2048
#define S_      32
#define C_FEAT  128
#define C_OUT   131   // 3 + 128

// Transposed features (b, n, c), f32 — module-owned static device memory (67 MB).
__device__ float g_ft[(size_t)B_ * N_ * C_FEAT];

// features (B, C, N) -> g_ft (B, N, C). 32x32 f32 LDS tile, coalesced both sides.
__global__ __launch_bounds__(256) void transpose_kernel(
    const float* __restrict__ f)
{
    __shared__ float tile[32][33];   // +1 pad breaks 32-stride conflicts
    int tx = threadIdx.x & 31, tr = threadIdx.x >> 5;   // 8 rows per pass
    int n0 = blockIdx.x * 32, c0 = blockIdx.y * 32, b = blockIdx.z;
    for (int r = tr; r < 32; r += 8)
        tile[r][tx] = f[((size_t)(b * C_FEAT + c0 + r)) * N_ + n0 + tx];
    __syncthreads();
    for (int r = tr; r < 32; r += 8)
        g_ft[((size_t)(b * N_ + n0 + r)) * C_FEAT + c0 + tx] = tile[tx][r];
}

// One 256-thread block per query (b,m). f32 in / f32 out.
// Distance replicates the numpy-f32 reference BIT-EXACTLY:
//   qq, pp: forward sequential  ((x^2 + y^2) + z^2)      [np pairwise_sum n<8]
//   dot:    REVERSED sequential ((z*z' + y*y') + x*x')   [np einsum descending
//           switch-fallthrough remainder, scalar mul+add, no FMA]
//   dist = fl32( fl32(qq+pp) - fl32(2*dot) );  mask = dist < f32(0.04) strict
//           [NEP-50: python 0.2*0.2 casts weak -> f32]
// Round-4/5 evidence: identical absmax 4.8125 under f32 vs f64 dist => the
// mismatch was op-order/boundary vs np, not precision; ~1-3 corrupted queries.
__global__ __launch_bounds__(256) void fused_kernel(
    const float* __restrict__ xyz,
    const float* __restrict__ new_xyz,
    float* __restrict__ out)
{
    __shared__ unsigned long long s_mask[4];
    __shared__ int s_fin[32];
    __shared__ float sF[32][132];    // 128 + 4 pad (row pitch 528 B, 16B-aligned)

    unsigned qid = blockIdx.x;            // b*2048 + m
    unsigned b = qid >> 11, m = qid & 2047u;
    unsigned w = threadIdx.x >> 6, lane = threadIdx.x & 63u;

    const float* q = new_xyz + (b * M_ + m) * 3;
    float qx = q[0], qy = q[1], qz = q[2];
    float qq = __fadd_rn(__fadd_rn(__fmul_rn(qx,qx), __fmul_rn(qy,qy)), __fmul_rn(qz,qz));

    const float* P = xyz + (size_t)b * N_ * 3;

    int done = 0;   // uniform across the block
    for (int base0 = 0; base0 < N_ && done < S_; base0 += 256) {
        int n = base0 + (int)(w * 64u + lane);
        float px = P[n*3+0], py = P[n*3+1], pz = P[n*3+2];
        float pp = __fadd_rn(__fadd_rn(__fmul_rn(px,px), __fmul_rn(py,py)), __fmul_rn(pz,pz));
        // np einsum d=3 remainder: accum = z*z'; accum += y*y'; accum += x*x'
        float dt = __fadd_rn(__fadd_rn(__fmul_rn(qz,pz), __fmul_rn(qy,py)), __fmul_rn(qx,px));
        float dist = __fsub_rn(__fadd_rn(qq, pp), __fmul_rn(2.0f, dt));

        unsigned long long mk = __ballot(dist < 0.04f);   // strict <, f32(0.04)
        if (lane == 0) s_mask[w] = mk;
        __syncthreads();

        unsigned long long m0 = s_mask[0], m1 = s_mask[1],
                           m2 = s_mask[2], m3 = s_mask[3];
        int c0 = __popcll(m0), c1 = __popcll(m1), c2 = __popcll(m2), c3 = __popcll(m3);
        int pre = done + ((w > 0) ? c0 : 0) + ((w > 1) ? c1 : 0) + ((w > 2) ? c2 : 0);
        if ((mk >> lane) & 1ull) {
            int rank = __popcll(mk & ((1ull << lane) - 1ull));
            int slot = pre + rank;
            if (slot < S_) s_fin[slot] = n;      // ascending: wave order x bit order
        }
        done += c0 + c1 + c2 + c3;               // uniform
        __syncthreads();                          // s_fin done; s_mask reusable
    }

    // Pad: slots [total,32) <- s_fin[0] if any valid, else 0 (reference semantics).
    int total = (done < S_) ? done : S_;
    if ((int)threadIdx.x >= total && threadIdx.x < S_)
        s_fin[threadIdx.x] = (done > 0) ? s_fin[0] : 0;
    __syncthreads();

    // Stage feature rows: 128 f32 = 32 float4; 8 threads/row x 4 float4 each.
    {
        int s = (int)threadIdx.x >> 3, ck = (int)threadIdx.x & 7;
        int n = s_fin[s];
        const float4* src = (const float4*)(g_ft + ((size_t)(b * N_ + n)) * C_FEAT);
        float4 v0 = src[ck];
        float4 v1 = src[ck + 8];
        float4 v2 = src[ck + 16];
        float4 v3 = src[ck + 24];
        *((float4*)&sF[s][(ck     ) * 4]) = v0;
        *((float4*)&sF[s][(ck +  8) * 4]) = v1;
        *((float4*)&sF[s][(ck + 16) * 4]) = v2;
        *((float4*)&sF[s][(ck + 24) * 4]) = v3;
    }
    __syncthreads();

    // Write 131 channels x 8 sample-quads -> float4 stores (16B, coalesced).
    for (int u = (int)threadIdx.x; u < C_OUT * 8; u += 256) {
        int ch = u >> 3;
        int sq = (u & 7) * 4;
        float r0, r1, r2, r3;
        if (ch < 3) {
            float qc = (ch == 0) ? qx : (ch == 1) ? qy : qz;
            int n0i = s_fin[sq + 0], n1i = s_fin[sq + 1];
            int n2i = s_fin[sq + 2], n3i = s_fin[sq + 3];
            r0 = __fsub_rn(P[n0i*3 + ch], qc);
            r1 = __fsub_rn(P[n1i*3 + ch], qc);
            r2 = __fsub_rn(P[n2i*3 + ch], qc);
            r3 = __fsub_rn(P[n3i*3 + ch], qc);
        } else {
            int c = ch - 3;
            r0 = sF[sq + 0][c];
            r1 = sF[sq + 1][c];
            r2 = sF[sq + 2][c];
            r3 = sF[sq + 3][c];
        }
        size_t off = (((size_t)(b * C_OUT + ch) * M_ + m) * S_) + sq;
        float4 v4; v4.x = r0; v4.y = r1; v4.z = r2; v4.w = r3;
        *((float4*)(out + off)) = v4;
    }
}

extern "C" void kernel_launch(void* const* d_in, const int* in_sizes, int n_in,
                              void* d_out, int out_size, void* d_ws, size_t ws_size,
                              hipStream_t stream) {
    const float* xyz      = (const float*)d_in[0];  // (8,8192,3) f32 (bf16-grid values)
    const float* new_xyz  = (const float*)d_in[1];  // (8,2048,3) f32
    const float* features = (const float*)d_in[2];  // (8,128,8192) f32
    float* out = (float*)d_out;                     // (8,131,2048,32) f32

    transpose_kernel<<<dim3(N_ / 32, C_FEAT / 32, B_), dim3(256), 0, stream>>>(features);
    fused_kernel<<<dim3(B_ * M_), dim3(256), 0, stream>>>(xyz, new_xyz, out);
}

// Round 7
// 348.186 us; speedup vs baseline: 1.0730x; 1.0730x over previous
//
#include <hip/hip_runtime.h>

#define B_      8
#define N_      8192
#define M_      2048
#define S_      32
#define C_FEAT  128
#define C_OUT   131   // 3 + 128

// Transposed features (b, n, c), f32 — module-owned static device memory (67 MB).
__device__ float g_ft[(size_t)B_ * N_ * C_FEAT];

// features (B, C, N) -> g_ft (B, N, C). 32x32 f32 LDS tile, coalesced both sides.
__global__ __launch_bounds__(256) void transpose_kernel(
    const float* __restrict__ f)
{
    __shared__ float tile[32][33];   // +1 pad breaks 32-stride conflicts
    int tx = threadIdx.x & 31, tr = threadIdx.x >> 5;   // 8 rows per pass
    int n0 = blockIdx.x * 32, c0 = blockIdx.y * 32, b = blockIdx.z;
    for (int r = tr; r < 32; r += 8)
        tile[r][tx] = f[((size_t)(b * C_FEAT + c0 + r)) * N_ + n0 + tx];
    __syncthreads();
    for (int r = tr; r < 32; r += 8)
        g_ft[((size_t)(b * N_ + n0 + r)) * C_FEAT + c0 + tx] = tile[tx][r];
}

// One 256-thread block per query (b,m). f32 in / f32 out.
// !!! DISTANCE BLOCK IS BIT-EXACT vs THE numpy-f32 REFERENCE — DO NOT TOUCH !!!
//   qq, pp: forward sequential  ((x^2 + y^2) + z^2)      [np pairwise_sum n<8]
//   dot:    REVERSED sequential ((z*z' + y*y') + x*x')   [np einsum d=3
//           descending switch-fallthrough remainder, scalar mul+add, no FMA]
//   dist = fl32( fl32(qq+pp) - fl32(2*dot) );  mask = dist < f32(0.04) strict
// Round 6: passed with absmax = 0.0 under exactly this formulation.
__global__ __launch_bounds__(256) void fused_kernel(
    const float* __restrict__ xyz,
    const float* __restrict__ new_xyz,
    float* __restrict__ out)
{
    __shared__ unsigned long long s_mask[8];
    __shared__ int s_fin[32];
    __shared__ float s_cx[32], s_cy[32], s_cz[32];   // coords of selected points
    __shared__ float sF[32][132];    // 128 + 4 pad (row pitch 528 B, 16B-aligned)

    unsigned qid = blockIdx.x;            // b*2048 + m
    unsigned b = qid >> 11, m = qid & 2047u;
    unsigned w = threadIdx.x >> 6, lane = threadIdx.x & 63u;

    const float* q = new_xyz + (b * M_ + m) * 3;
    float qx = q[0], qy = q[1], qz = q[2];
    float qq = __fadd_rn(__fadd_rn(__fmul_rn(qx,qx), __fmul_rn(qy,qy)), __fmul_rn(qz,qz));

    const float* P = xyz + (size_t)b * N_ * 3;

    int done = 0;   // uniform across the block
    for (int base = 0; base < N_ && done < S_; base += 512) {
        // eval 0 covers [base, base+256), eval 1 covers [base+256, base+512);
        // global ascending order = (eval, wave, lane-bit) — masks concat in
        // order s_mask[0..3] (eval0 w0..w3) then s_mask[4..7] (eval1 w0..w3).
        int n0 = base + (int)(w * 64u + lane);
        int n1 = n0 + 256;
        float px0 = P[n0*3+0], py0 = P[n0*3+1], pz0 = P[n0*3+2];
        float px1 = P[n1*3+0], py1 = P[n1*3+1], pz1 = P[n1*3+2];

        float pp0 = __fadd_rn(__fadd_rn(__fmul_rn(px0,px0), __fmul_rn(py0,py0)), __fmul_rn(pz0,pz0));
        float dt0 = __fadd_rn(__fadd_rn(__fmul_rn(qz,pz0), __fmul_rn(qy,py0)), __fmul_rn(qx,px0));
        float d0  = __fsub_rn(__fadd_rn(qq, pp0), __fmul_rn(2.0f, dt0));
        float pp1 = __fadd_rn(__fadd_rn(__fmul_rn(px1,px1), __fmul_rn(py1,py1)), __fmul_rn(pz1,pz1));
        float dt1 = __fadd_rn(__fadd_rn(__fmul_rn(qz,pz1), __fmul_rn(qy,py1)), __fmul_rn(qx,px1));
        float d1  = __fsub_rn(__fadd_rn(qq, pp1), __fmul_rn(2.0f, dt1));

        unsigned long long mk0 = __ballot(d0 < 0.04f);   // strict <, f32(0.04)
        unsigned long long mk1 = __ballot(d1 < 0.04f);
        if (lane == 0) { s_mask[w] = mk0; s_mask[4 + w] = mk1; }
        __syncthreads();

        int c[8], tot = 0;
        #pragma unroll
        for (int k = 0; k < 8; k++) { c[k] = __popcll(s_mask[k]); tot += c[k]; }
        int pre0 = done, pre1 = done;
        #pragma unroll
        for (int k = 0; k < 8; k++) {
            if (k < (int)w)     pre0 += c[k];
            if (k < (int)(4+w)) pre1 += c[k];
        }
        if ((mk0 >> lane) & 1ull) {
            int slot = pre0 + __popcll(mk0 & ((1ull << lane) - 1ull));
            if (slot < S_) { s_fin[slot] = n0; s_cx[slot] = px0; s_cy[slot] = py0; s_cz[slot] = pz0; }
        }
        if ((mk1 >> lane) & 1ull) {
            int slot = pre1 + __popcll(mk1 & ((1ull << lane) - 1ull));
            if (slot < S_) { s_fin[slot] = n1; s_cx[slot] = px1; s_cy[slot] = py1; s_cz[slot] = pz1; }
        }
        done += tot;                              // uniform
        __syncthreads();                          // s_fin/s_c* done; s_mask reusable
    }

    // Pad: slots [total,32) <- slot 0's index+coords if any valid, else idx 0.
    int total = (done < S_) ? done : S_;
    if ((int)threadIdx.x >= total && threadIdx.x < S_) {
        if (done > 0) {
            s_fin[threadIdx.x] = s_fin[0];
            s_cx[threadIdx.x] = s_cx[0]; s_cy[threadIdx.x] = s_cy[0]; s_cz[threadIdx.x] = s_cz[0];
        } else {
            s_fin[threadIdx.x] = 0;
            s_cx[threadIdx.x] = P[0]; s_cy[threadIdx.x] = P[1]; s_cz[threadIdx.x] = P[2];
        }
    }
    __syncthreads();

    // Stage feature rows: 128 f32 = 32 float4; 8 threads/row x 4 float4 each.
    {
        int s = (int)threadIdx.x >> 3, ck = (int)threadIdx.x & 7;
        int n = s_fin[s];
        const float4* src = (const float4*)(g_ft + ((size_t)(b * N_ + n)) * C_FEAT);
        float4 v0 = src[ck];
        float4 v1 = src[ck + 8];
        float4 v2 = src[ck + 16];
        float4 v3 = src[ck + 24];
        *((float4*)&sF[s][(ck     ) * 4]) = v0;
        *((float4*)&sF[s][(ck +  8) * 4]) = v1;
        *((float4*)&sF[s][(ck + 16) * 4]) = v2;
        *((float4*)&sF[s][(ck + 24) * 4]) = v3;
    }
    __syncthreads();

    // Write 131 channels x 8 sample-quads -> float4 stores (16B, coalesced).
    for (int u = (int)threadIdx.x; u < C_OUT * 8; u += 256) {
        int ch = u >> 3;
        int sq = (u & 7) * 4;
        float r0, r1, r2, r3;
        if (ch < 3) {
            float qc = (ch == 0) ? qx : (ch == 1) ? qy : qz;
            const float* sc = (ch == 0) ? s_cx : (ch == 1) ? s_cy : s_cz;
            r0 = __fsub_rn(sc[sq + 0], qc);
            r1 = __fsub_rn(sc[sq + 1], qc);
            r2 = __fsub_rn(sc[sq + 2], qc);
            r3 = __fsub_rn(sc[sq + 3], qc);
        } else {
            int c = ch - 3;
            r0 = sF[sq + 0][c];
            r1 = sF[sq + 1][c];
            r2 = sF[sq + 2][c];
            r3 = sF[sq + 3][c];
        }
        size_t off = (((size_t)(b * C_OUT + ch) * M_ + m) * S_) + sq;
        float4 v4; v4.x = r0; v4.y = r1; v4.z = r2; v4.w = r3;
        *((float4*)(out + off)) = v4;
    }
}

extern "C" void kernel_launch(void* const* d_in, const int* in_sizes, int n_in,
                              void* d_out, int out_size, void* d_ws, size_t ws_size,
                              hipStream_t stream) {
    const float* xyz      = (const float*)d_in[0];  // (8,8192,3) f32 (bf16-grid values)
    const float* new_xyz  = (const float*)d_in[1];  // (8,2048,3) f32
    const float* features = (const float*)d_in[2];  // (8,128,8192) f32
    float* out = (float*)d_out;                     // (8,131,2048,32) f32

    transpose_kernel<<<dim3(N_ / 32, C_FEAT / 32, B_), dim3(256), 0, stream>>>(features);
    fused_kernel<<<dim3(B_ * M_), dim3(256), 0, stream>>>(xyz, new_xyz, out);
}

// Round 8
// 329.900 us; speedup vs baseline: 1.1325x; 1.0554x over previous
//
#include <hip/hip_runtime.h>

#define B_      8
#define N_      8192
#define M_      2048
#define S_      32
#define C_FEAT  128
#define C_OUT   131   // 3 + 128

// Transposed features (b, n, c), f32 — module-owned static device memory (67 MB).
__device__ float g_ft[(size_t)B_ * N_ * C_FEAT];

// features (B, C, N) -> g_ft (B, N, C). 32x32 f32 LDS tile, coalesced both sides.
__global__ __launch_bounds__(256) void transpose_kernel(
    const float* __restrict__ f)
{
    __shared__ float tile[32][33];   // +1 pad breaks 32-stride conflicts
    int tx = threadIdx.x & 31, tr = threadIdx.x >> 5;   // 8 rows per pass
    int n0 = blockIdx.x * 32, c0 = blockIdx.y * 32, b = blockIdx.z;
    for (int r = tr; r < 32; r += 8)
        tile[r][tx] = f[((size_t)(b * C_FEAT + c0 + r)) * N_ + n0 + tx];
    __syncthreads();
    for (int r = tr; r < 32; r += 8)
        g_ft[((size_t)(b * N_ + n0 + r)) * C_FEAT + c0 + tx] = tile[tx][r];
}

// One 256-thread block per query (b,m). f32 in / f32 out.
// !!! DISTANCE BLOCK IS BIT-EXACT vs THE numpy-f32 REFERENCE — DO NOT TOUCH !!!
//   qq, pp: forward sequential  ((x^2 + y^2) + z^2)      [np pairwise_sum n<8]
//   dot:    REVERSED sequential ((z*z' + y*y') + x*x')   [np einsum d=3
//           descending switch-fallthrough remainder, scalar mul+add, no FMA]
//   dist = fl32( fl32(qq+pp) - fl32(2*dot) );  mask = dist < f32(0.04) strict
// Round 6: passed with absmax = 0.0 under exactly this formulation.
__global__ __launch_bounds__(256) void fused_kernel(
    const float* __restrict__ xyz,
    const float* __restrict__ new_xyz,
    float* __restrict__ out)
{
    __shared__ unsigned long long s_mask[8];
    __shared__ int s_fin[32];
    __shared__ float s_cx[32], s_cy[32], s_cz[32];   // coords of selected points
    __shared__ float sF[32][132];    // 128 + 4 pad (row pitch 528 B, 16B-aligned)

    // XCD-aware swizzle: dispatch round-robins blockIdx across the 8 XCDs, so
    // b = blockIdx&7 pins each batch to one XCD. Ball-query early-exit makes
    // selected rows concentrate at low n (~1-2 MB hot per batch); one batch's
    // whole g_ft slice is 4 MB = one XCD L2 => gathers become XCD-local L2 hits
    // instead of replicated L3 traffic. Speed heuristic only (bijective remap).
    unsigned i = blockIdx.x;
    unsigned b = i & 7u, m = i >> 3;      // qid = b*2048 + m
    unsigned w = threadIdx.x >> 6, lane = threadIdx.x & 63u;

    const float* q = new_xyz + (b * M_ + m) * 3;
    float qx = q[0], qy = q[1], qz = q[2];
    float qq = __fadd_rn(__fadd_rn(__fmul_rn(qx,qx), __fmul_rn(qy,qy)), __fmul_rn(qz,qz));

    const float* P = xyz + (size_t)b * N_ * 3;

    int done = 0;   // uniform across the block
    for (int base = 0; base < N_ && done < S_; base += 512) {
        // eval 0 covers [base, base+256), eval 1 covers [base+256, base+512);
        // global ascending order = (eval, wave, lane-bit) — masks concat in
        // order s_mask[0..3] (eval0 w0..w3) then s_mask[4..7] (eval1 w0..w3).
        int n0 = base + (int)(w * 64u + lane);
        int n1 = n0 + 256;
        float px0 = P[n0*3+0], py0 = P[n0*3+1], pz0 = P[n0*3+2];
        float px1 = P[n1*3+0], py1 = P[n1*3+1], pz1 = P[n1*3+2];

        float pp0 = __fadd_rn(__fadd_rn(__fmul_rn(px0,px0), __fmul_rn(py0,py0)), __fmul_rn(pz0,pz0));
        float dt0 = __fadd_rn(__fadd_rn(__fmul_rn(qz,pz0), __fmul_rn(qy,py0)), __fmul_rn(qx,px0));
        float d0  = __fsub_rn(__fadd_rn(qq, pp0), __fmul_rn(2.0f, dt0));
        float pp1 = __fadd_rn(__fadd_rn(__fmul_rn(px1,px1), __fmul_rn(py1,py1)), __fmul_rn(pz1,pz1));
        float dt1 = __fadd_rn(__fadd_rn(__fmul_rn(qz,pz1), __fmul_rn(qy,py1)), __fmul_rn(qx,px1));
        float d1  = __fsub_rn(__fadd_rn(qq, pp1), __fmul_rn(2.0f, dt1));

        unsigned long long mk0 = __ballot(d0 < 0.04f);   // strict <, f32(0.04)
        unsigned long long mk1 = __ballot(d1 < 0.04f);
        if (lane == 0) { s_mask[w] = mk0; s_mask[4 + w] = mk1; }
        __syncthreads();

        int c[8], tot = 0;
        #pragma unroll
        for (int k = 0; k < 8; k++) { c[k] = __popcll(s_mask[k]); tot += c[k]; }
        int pre0 = done, pre1 = done;
        #pragma unroll
        for (int k = 0; k < 8; k++) {
            if (k < (int)w)     pre0 += c[k];
            if (k < (int)(4+w)) pre1 += c[k];
        }
        if ((mk0 >> lane) & 1ull) {
            int slot = pre0 + __popcll(mk0 & ((1ull << lane) - 1ull));
            if (slot < S_) { s_fin[slot] = n0; s_cx[slot] = px0; s_cy[slot] = py0; s_cz[slot] = pz0; }
        }
        if ((mk1 >> lane) & 1ull) {
            int slot = pre1 + __popcll(mk1 & ((1ull << lane) - 1ull));
            if (slot < S_) { s_fin[slot] = n1; s_cx[slot] = px1; s_cy[slot] = py1; s_cz[slot] = pz1; }
        }
        done += tot;                              // uniform
        __syncthreads();                          // s_fin/s_c* done; s_mask reusable
    }

    // Pad: slots [total,32) <- slot 0's index+coords if any valid, else idx 0.
    int total = (done < S_) ? done : S_;
    if ((int)threadIdx.x >= total && threadIdx.x < S_) {
        if (done > 0) {
            s_fin[threadIdx.x] = s_fin[0];
            s_cx[threadIdx.x] = s_cx[0]; s_cy[threadIdx.x] = s_cy[0]; s_cz[threadIdx.x] = s_cz[0];
        } else {
            s_fin[threadIdx.x] = 0;
            s_cx[threadIdx.x] = P[0]; s_cy[threadIdx.x] = P[1]; s_cz[threadIdx.x] = P[2];
        }
    }
    __syncthreads();

    // Stage feature rows: 128 f32 = 32 float4; 8 threads/row x 4 float4 each.
    {
        int s = (int)threadIdx.x >> 3, ck = (int)threadIdx.x & 7;
        int n = s_fin[s];
        const float4* src = (const float4*)(g_ft + ((size_t)(b * N_ + n)) * C_FEAT);
        float4 v0 = src[ck];
        float4 v1 = src[ck + 8];
        float4 v2 = src[ck + 16];
        float4 v3 = src[ck + 24];
        *((float4*)&sF[s][(ck     ) * 4]) = v0;
        *((float4*)&sF[s][(ck +  8) * 4]) = v1;
        *((float4*)&sF[s][(ck + 16) * 4]) = v2;
        *((float4*)&sF[s][(ck + 24) * 4]) = v3;
    }
    __syncthreads();

    // Write 131 channels x 8 sample-quads -> float4 stores (16B, coalesced).
    for (int u = (int)threadIdx.x; u < C_OUT * 8; u += 256) {
        int ch = u >> 3;
        int sq = (u & 7) * 4;
        float r0, r1, r2, r3;
        if (ch < 3) {
            float qc = (ch == 0) ? qx : (ch == 1) ? qy : qz;
            const float* sc = (ch == 0) ? s_cx : (ch == 1) ? s_cy : s_cz;
            r0 = __fsub_rn(sc[sq + 0], qc);
            r1 = __fsub_rn(sc[sq + 1], qc);
            r2 = __fsub_rn(sc[sq + 2], qc);
            r3 = __fsub_rn(sc[sq + 3], qc);
        } else {
            int c = ch - 3;
            r0 = sF[sq + 0][c];
            r1 = sF[sq + 1][c];
            r2 = sF[sq + 2][c];
            r3 = sF[sq + 3][c];
        }
        size_t off = (((size_t)(b * C_OUT + ch) * M_ + m) * S_) + sq;
        float4 v4; v4.x = r0; v4.y = r1; v4.z = r2; v4.w = r3;
        *((float4*)(out + off)) = v4;
    }
}

extern "C" void kernel_launch(void* const* d_in, const int* in_sizes, int n_in,
                              void* d_out, int out_size, void* d_ws, size_t ws_size,
                              hipStream_t stream) {
    const float* xyz      = (const float*)d_in[0];  // (8,8192,3) f32 (bf16-grid values)
    const float* new_xyz  = (const float*)d_in[1];  // (8,2048,3) f32
    const float* features = (const float*)d_in[2];  // (8,128,8192) f32
    float* out = (float*)d_out;                     // (8,131,2048,32) f32

    transpose_kernel<<<dim3(N_ / 32, C_FEAT / 32, B_), dim3(256), 0, stream>>>(features);
    fused_kernel<<<dim3(B_ * M_), dim3(256), 0, stream>>>(xyz, new_xyz, out);
}